// Round 2
// baseline (573.312 us; speedup 1.0000x reference)
//
#include <hip/hip_runtime.h>

#define Tn 1024
#define Kn 8
#define En 64
#define Hn 1024
#define In 512
#define RCAP 256   // max rows kept per expert (mean load 128, sigma ~11 -> safe)

typedef __attribute__((ext_vector_type(8))) short bf16x8;
typedef __attribute__((ext_vector_type(4))) float f32x4;

__device__ __forceinline__ short f2bf(float f) {
  unsigned u = __float_as_uint(f);
  unsigned r = (u + 0x7FFFu + ((u >> 16) & 1u)) >> 16;  // RNE
  return (short)r;
}
__device__ __forceinline__ float bf2f(short s) {
  return __uint_as_float(((unsigned)(unsigned short)s) << 16);
}
__device__ __forceinline__ void load_lds16(const void* g, void* l) {
  __builtin_amdgcn_global_load_lds(
      (const __attribute__((address_space(1))) void*)g,
      (__attribute__((address_space(3))) void*)l, 16, 0, 0);
}

// ---------------- kernel 1: route + gather (fp32 -> bf16) ----------------
// one wave per (t,k) pair; atomicAdd assigns the expert slot (order-free:
// per-row independence makes any within-expert permutation equivalent).
__global__ __launch_bounds__(256) void k_route(
    const float* __restrict__ hs, const int* __restrict__ idx,
    int* __restrict__ cnt, int* __restrict__ p2r, short* __restrict__ Xe) {
  const int pair = blockIdx.x * 4 + (threadIdx.x >> 6);
  const int lane = threadIdx.x & 63;
  const int e = idx[pair];
  int p = 0;
  if (lane == 0) p = atomicAdd(&cnt[e], 1);
  p = __shfl(p, 0);
  if (lane == 0) p2r[pair] = e * RCAP + min(p, RCAP - 1);
  if (p < RCAP) {
    const int t = pair >> 3;
    const float* src = hs + (size_t)t * Hn;
    short* dst = Xe + (size_t)(e * RCAP + p) * Hn;
#pragma unroll
    for (int j = 0; j < 4; ++j) {
      const int c0 = j * 256 + lane * 4;
      float4 v = *(const float4*)&src[c0];
      short4 s;
      s.x = f2bf(v.x); s.y = f2bf(v.y); s.z = f2bf(v.z); s.w = f2bf(v.w);
      *(short4*)&dst[c0] = s;
    }
  }
}

// ---------------- kernel 2: per-expert X @ Wgu^T, fused SwiGLU ----------------
// block tile: 128 rows x 128 gu-cols (= 64 gate + 64 up -> 64 h cols), BK=32.
// waves split on M so gate(nf) and up(nf+4) live in the same lane/reg.
__global__ __launch_bounds__(256) void k_gemm1(
    const short* __restrict__ Xe, const float* __restrict__ gup,
    const int* __restrict__ cnt, short* __restrict__ hb) {
  const int e = blockIdx.z, mb = blockIdx.y, nb = blockIdx.x;
  const int ne = min(cnt[e], RCAP);
  if (mb * 128 >= ne) return;
  __shared__ short As[128][32];
  __shared__ short Bs[128][32];
  const int tid = threadIdx.x;
  const int lane = tid & 63, wid = tid >> 6;
  const int base_row = e * RCAP + mb * 128;

  const short* aptr[2];
  short* ldst[2];
#pragma unroll
  for (int it = 0; it < 2; ++it) {
    const int seg = wid * 2 + it;               // 8 segs of 16 rows
    const int r = seg * 16 + (lane >> 2);
    const int cb = (lane & 3) * 8;
    aptr[it] = &Xe[(size_t)(base_row + r) * Hn + cb];
    ldst[it] = &As[seg * 16][0];                // wave-uniform LDS base
  }
  const float* bsrc[4];
  short* bdst[4];
#pragma unroll
  for (int it = 0; it < 4; ++it) {
    const int c2 = it * 256 + tid;
    const int row = c2 >> 3, cg = c2 & 7;
    const int o = (row < 64) ? (nb * 64 + row) : (In + nb * 64 + (row - 64));
    bsrc[it] = &gup[(size_t)e * (2 * In) * Hn + (size_t)o * Hn + cg * 4];
    bdst[it] = &Bs[row][cg * 4];
  }

  f32x4 acc[2][8];
#pragma unroll
  for (int mf = 0; mf < 2; ++mf)
#pragma unroll
    for (int nf = 0; nf < 8; ++nf) acc[mf][nf] = (f32x4)(0.f);

  for (int k0 = 0; k0 < Hn; k0 += 32) {
#pragma unroll
    for (int it = 0; it < 2; ++it) load_lds16(aptr[it] + k0, ldst[it]);
#pragma unroll
    for (int it = 0; it < 4; ++it) {
      float4 v = *(const float4*)(bsrc[it] + k0);
      short4 s;
      s.x = f2bf(v.x); s.y = f2bf(v.y); s.z = f2bf(v.z); s.w = f2bf(v.w);
      *(short4*)bdst[it] = s;
    }
    __syncthreads();
    bf16x8 a[2], b[8];
#pragma unroll
    for (int mf = 0; mf < 2; ++mf)
      a[mf] = *(const bf16x8*)&As[wid * 32 + mf * 16 + (lane & 15)][(lane >> 4) * 8];
#pragma unroll
    for (int nf = 0; nf < 8; ++nf)
      b[nf] = *(const bf16x8*)&Bs[nf * 16 + (lane & 15)][(lane >> 4) * 8];
#pragma unroll
    for (int nf = 0; nf < 8; ++nf)
#pragma unroll
      for (int mf = 0; mf < 2; ++mf)
        acc[mf][nf] = __builtin_amdgcn_mfma_f32_16x16x32_bf16(a[mf], b[nf], acc[mf][nf], 0, 0, 0);
    __syncthreads();
  }

#pragma unroll
  for (int mf = 0; mf < 2; ++mf)
#pragma unroll
    for (int nf = 0; nf < 4; ++nf)
#pragma unroll
      for (int r = 0; r < 4; ++r) {
        const float g = acc[mf][nf][r];
        const float u = acc[mf][nf + 4][r];
        const float hv = (g / (1.f + __expf(-g))) * u;   // silu(g)*u
        const int rl = wid * 32 + mf * 16 + (lane >> 4) * 4 + r;
        const int hc = nb * 64 + nf * 16 + (lane & 15);
        hb[(size_t)(base_row + rl) * In + hc] = f2bf(hv);
      }
}

// ---------------- kernel 3: per-expert h @ Wd^T ----------------
__global__ __launch_bounds__(256) void k_gemm2(
    const short* __restrict__ hb, const float* __restrict__ dp,
    const int* __restrict__ cnt, short* __restrict__ yd) {
  const int e = blockIdx.z, mb = blockIdx.y, nb = blockIdx.x;
  const int ne = min(cnt[e], RCAP);
  if (mb * 128 >= ne) return;
  __shared__ short As[128][32];
  __shared__ short Bs[128][32];
  const int tid = threadIdx.x;
  const int lane = tid & 63, wid = tid >> 6;
  const int base_row = e * RCAP + mb * 128;

  const short* aptr[2];
  short* ldst[2];
#pragma unroll
  for (int it = 0; it < 2; ++it) {
    const int seg = wid * 2 + it;
    const int r = seg * 16 + (lane >> 2);
    const int cb = (lane & 3) * 8;
    aptr[it] = &hb[(size_t)(base_row + r) * In + cb];
    ldst[it] = &As[seg * 16][0];
  }
  const float* bsrc[4];
  short* bdst[4];
#pragma unroll
  for (int it = 0; it < 4; ++it) {
    const int c2 = it * 256 + tid;
    const int row = c2 >> 3, cg = c2 & 7;
    const int o = nb * 128 + row;
    bsrc[it] = &dp[((size_t)e * Hn + o) * In + cg * 4];
    bdst[it] = &Bs[row][cg * 4];
  }

  f32x4 acc[2][8];
#pragma unroll
  for (int mf = 0; mf < 2; ++mf)
#pragma unroll
    for (int nf = 0; nf < 8; ++nf) acc[mf][nf] = (f32x4)(0.f);

  for (int k0 = 0; k0 < In; k0 += 32) {
#pragma unroll
    for (int it = 0; it < 2; ++it) load_lds16(aptr[it] + k0, ldst[it]);
#pragma unroll
    for (int it = 0; it < 4; ++it) {
      float4 v = *(const float4*)(bsrc[it] + k0);
      short4 s;
      s.x = f2bf(v.x); s.y = f2bf(v.y); s.z = f2bf(v.z); s.w = f2bf(v.w);
      *(short4*)bdst[it] = s;
    }
    __syncthreads();
    bf16x8 a[2], b[8];
#pragma unroll
    for (int mf = 0; mf < 2; ++mf)
      a[mf] = *(const bf16x8*)&As[wid * 32 + mf * 16 + (lane & 15)][(lane >> 4) * 8];
#pragma unroll
    for (int nf = 0; nf < 8; ++nf)
      b[nf] = *(const bf16x8*)&Bs[nf * 16 + (lane & 15)][(lane >> 4) * 8];
#pragma unroll
    for (int nf = 0; nf < 8; ++nf)
#pragma unroll
      for (int mf = 0; mf < 2; ++mf)
        acc[mf][nf] = __builtin_amdgcn_mfma_f32_16x16x32_bf16(a[mf], b[nf], acc[mf][nf], 0, 0, 0);
    __syncthreads();
  }

#pragma unroll
  for (int mf = 0; mf < 2; ++mf)
#pragma unroll
    for (int nf = 0; nf < 8; ++nf)
#pragma unroll
      for (int r = 0; r < 4; ++r) {
        const int rl = wid * 32 + mf * 16 + (lane >> 4) * 4 + r;
        const int col = nb * 128 + nf * 16 + (lane & 15);
        yd[(size_t)(base_row + rl) * Hn + col] = f2bf(acc[mf][nf][r]);
      }
}

// ---------------- kernel 4: weighted combine (deterministic gather) ----------------
__global__ __launch_bounds__(256) void k_combine(
    const short* __restrict__ yd, const int* __restrict__ p2r,
    const float* __restrict__ tkw, float* __restrict__ out) {
  const int t = blockIdx.x;
  const int c = threadIdx.x * 4;
  float4 acc = make_float4(0.f, 0.f, 0.f, 0.f);
#pragma unroll
  for (int k = 0; k < Kn; ++k) {
    const int i = t * Kn + k;
    const int row = p2r[i];
    const float w = tkw[i];
    short4 v = *(const short4*)&yd[(size_t)row * Hn + c];
    acc.x += w * bf2f(v.x);
    acc.y += w * bf2f(v.y);
    acc.z += w * bf2f(v.z);
    acc.w += w * bf2f(v.w);
  }
  *(float4*)&out[(size_t)t * Hn + c] = acc;
}

extern "C" void kernel_launch(void* const* d_in, const int* in_sizes, int n_in,
                              void* d_out, int out_size, void* d_ws, size_t ws_size,
                              hipStream_t stream) {
  const float* hs = (const float*)d_in[0];
  const int* idx = (const int*)d_in[1];
  const float* tkw = (const float*)d_in[2];
  const float* gup = (const float*)d_in[3];
  const float* dp = (const float*)d_in[4];
  float* out = (float*)d_out;

  char* w = (char*)d_ws;
  int* cnt = (int*)(w + 0);                 //      256 B
  int* p2r = (int*)(w + 4096);              //   32 KB
  short* Xe = (short*)(w + (1u << 20));     //   32 MB  (E*RCAP*H bf16)
  short* hb = (short*)(w + 34603008u);      //   16 MB  (E*RCAP*I bf16)
  short* yd = (short*)(w + 51380224u);      //   32 MB  (E*RCAP*H bf16)
  // total ws needed ~85 MB

  hipMemsetAsync(cnt, 0, En * sizeof(int), stream);
  k_route<<<dim3((Tn * Kn) / 4), dim3(256), 0, stream>>>(hs, idx, cnt, p2r, Xe);
  k_gemm1<<<dim3(In / 64, RCAP / 128, En), dim3(256), 0, stream>>>(Xe, gup, cnt, hb);
  k_gemm2<<<dim3(Hn / 128, RCAP / 128, En), dim3(256), 0, stream>>>(hb, dp, cnt, yd);
  k_combine<<<dim3(Tn), dim3(256), 0, stream>>>(yd, p2r, tkw, out);
}